// Round 2
// baseline (112.404 us; speedup 1.0000x reference)
//
#include <hip/hip_runtime.h>
#include <hip/hip_bf16.h>
#include <hip/hip_cooperative_groups.h>

namespace cg = cooperative_groups;

#define B 4
#define S 2048
#define D 512
#define P 16
#define NC 64   // chunks over sequence
#define CL 32   // chunk length = S/NC

// One cooperative kernel. Block = (b, c), 512 threads (thread = d in phases B/D).
// Phase A: prods + softmax for the chunk's 32 rows -> LDS.
// Phase B: chunk totals -> global T.
// grid.sync
// Phase C: exclusive prefix over chunks (first 64 blocks).
// grid.sync
// Phase D: seeded in-chunk scan with fused softmax-weighted output.
__global__ __launch_bounds__(512) void fused(const float* __restrict__ x,
                                             const float* __restrict__ proxy,
                                             float* __restrict__ T,
                                             float* __restrict__ out) {
    __shared__ float s_pr[CL][P];
    __shared__ float s_w [CL][P];

    const int c    = blockIdx.x & (NC - 1);
    const int b    = blockIdx.x >> 6;
    const int tid  = threadIdx.x;
    const int lane = tid & 63;
    const int wv   = tid >> 6;          // wave id 0..7
    const int bs0  = b * S + c * CL;

    // ---------------- Phase A: prods + softmax (wave wv owns rows wv*4..wv*4+3)
#pragma unroll
    for (int r = 0; r < 4; ++r) {
        const int sl = wv * 4 + r;
        const int bs = bs0 + sl;
        const float* xr = x + (size_t)bs * D + lane * 8;
        float4 xa = *(const float4*)xr;
        float4 xb = *(const float4*)(xr + 4);

        float part[P];
#pragma unroll
        for (int p = 0; p < P; ++p) {
            const float* pr = proxy + p * D + lane * 8;
            float4 pa = *(const float4*)pr;
            float4 pb = *(const float4*)(pr + 4);
            part[p] = xa.x*pa.x + xa.y*pa.y + xa.z*pa.z + xa.w*pa.w
                    + xb.x*pb.x + xb.y*pb.y + xb.z*pb.z + xb.w*pb.w;
        }
#pragma unroll
        for (int p = 0; p < P; ++p) {
            float v = part[p];
#pragma unroll
            for (int off = 32; off > 0; off >>= 1) v += __shfl_xor(v, off);
            part[p] = v;
        }
        float m = part[0];
#pragma unroll
        for (int p = 1; p < P; ++p) m = fmaxf(m, part[p]);
        float e[P];
        float den = 0.f;
#pragma unroll
        for (int p = 0; p < P; ++p) { e[p] = __expf((part[p] - m) * 0.25f); den += e[p]; }
        float inv = 1.f / den;

        int lp = lane & 15;
        float myp = part[0], mye = e[0];
#pragma unroll
        for (int p = 1; p < P; ++p) {
            bool sel = (lp == p);
            myp = sel ? part[p] : myp;
            mye = sel ? e[p]    : mye;
        }
        if (lane < P) {
            s_pr[sl][lane] = myp;
            s_w [sl][lane] = mye * inv;
        }
    }
    __syncthreads();

    // ---------------- Phase B: chunk totals -> T[b,c,p,d]
    {
        const int d = tid;
        float acc[P];
#pragma unroll
        for (int p = 0; p < P; ++p) acc[p] = 0.f;
#pragma unroll 4
        for (int i = 0; i < CL; ++i) {
            float xv = x[(size_t)(bs0 + i) * D + d];
#pragma unroll
            for (int p = 0; p < P; ++p) acc[p] = fmaf(s_pr[i][p], xv, acc[p]);
        }
        size_t tb = (size_t)blockIdx.x * (P * D) + d;
#pragma unroll
        for (int p = 0; p < P; ++p) T[tb + p * D] = acc[p];
    }

    cg::this_grid().sync();

    // ---------------- Phase C: exclusive prefix over chunks (blocks 0..63)
    if (blockIdx.x < (B * P * D) / 512) {
        int t  = blockIdx.x * 512 + tid;
        int d  = t & (D - 1);
        int p  = (t >> 9) & (P - 1);
        int bb = t >> 13;
        size_t base = ((size_t)bb * NC * P + p) * D + d;
        float run = 0.f;
#pragma unroll 8
        for (int cc = 0; cc < NC; ++cc) {
            size_t idx = base + (size_t)cc * (P * D);
            float v = T[idx];
            T[idx] = run;
            run += v;
        }
    }

    cg::this_grid().sync();

    // ---------------- Phase D: apply
    {
        const int d = tid;
        float st[P];
        size_t tb = (size_t)blockIdx.x * (P * D) + d;
#pragma unroll
        for (int p = 0; p < P; ++p) st[p] = T[tb + p * D];

#pragma unroll 2
        for (int i = 0; i < CL; ++i) {
            const int bs = bs0 + i;
            float xv = x[(size_t)bs * D + d];
            float o = 0.f;
#pragma unroll
            for (int p = 0; p < P; ++p) {
                st[p] = fmaf(s_pr[i][p], xv, st[p]);
                o = fmaf(s_w[i][p], st[p], o);
            }
            out[(size_t)bs * D + d] = o;
        }
    }
}

extern "C" void kernel_launch(void* const* d_in, const int* in_sizes, int n_in,
                              void* d_out, int out_size, void* d_ws, size_t ws_size,
                              hipStream_t stream) {
    const float* x     = (const float*)d_in[0];
    const float* proxy = (const float*)d_in[1];
    float* out = (float*)d_out;
    float* T   = (float*)d_ws;          // B*NC*P*D floats = 8 MiB

    void* args[] = { (void*)&x, (void*)&proxy, (void*)&T, (void*)&out };
    hipLaunchCooperativeKernel((void*)fused, dim3(B * NC), dim3(512), args, 0, stream);
}

// Round 3
// 54.294 us; speedup vs baseline: 2.0703x; 2.0703x over previous
//
#include <hip/hip_runtime.h>
#include <hip/hip_bf16.h>

#define B 4
#define S 2048
#define D 512
#define P 16
#define NC 64   // chunks over sequence
#define CL 32   // chunk length = S/NC

// ---------------------------------------------------------------------------
// Kernel 1: prods[b,s,p] = dot(proxy[p,:], x[b,s,:]); w = softmax_p(prods/4).
// One wave per (b,s) row. Lane-interleaved merge-tree reduction:
// 16 partials -> 1 register in 4 steps; lane l ends holding total for p=l&15.
// ---------------------------------------------------------------------------
__global__ __launch_bounds__(256) void k_prods(const float* __restrict__ x,
                                               const float* __restrict__ proxy,
                                               float* __restrict__ prods,
                                               float* __restrict__ wgt) {
    int wid  = (blockIdx.x * blockDim.x + threadIdx.x) >> 6;  // bs index
    int lane = threadIdx.x & 63;
    if (wid >= B * S) return;

    const float* xr = x + (size_t)wid * D + lane * 8;
    float4 xa = *(const float4*)xr;
    float4 xb = *(const float4*)(xr + 4);

    float part[P];
#pragma unroll
    for (int p = 0; p < P; ++p) {
        const float* pr = proxy + p * D + lane * 8;
        float4 pa = *(const float4*)pr;
        float4 pb = *(const float4*)(pr + 4);
        part[p] = xa.x*pa.x + xa.y*pa.y + xa.z*pa.z + xa.w*pa.w
                + xb.x*pb.x + xb.y*pb.y + xb.z*pb.z + xb.w*pb.w;
    }

    // merge-tree: fold register count with lane bits 1,2,4,8
    float a8[8];
#pragma unroll
    for (int k = 0; k < 8; ++k) {
        bool hi = lane & 1;
        float mine = hi ? part[2*k+1] : part[2*k];
        float oth  = hi ? part[2*k]   : part[2*k+1];
        a8[k] = mine + __shfl_xor(oth, 1);
    }
    float a4[4];
#pragma unroll
    for (int k = 0; k < 4; ++k) {
        bool hi = lane & 2;
        float mine = hi ? a8[2*k+1] : a8[2*k];
        float oth  = hi ? a8[2*k]   : a8[2*k+1];
        a4[k] = mine + __shfl_xor(oth, 2);
    }
    float a2[2];
#pragma unroll
    for (int k = 0; k < 2; ++k) {
        bool hi = lane & 4;
        float mine = hi ? a4[2*k+1] : a4[2*k];
        float oth  = hi ? a4[2*k]   : a4[2*k+1];
        a2[k] = mine + __shfl_xor(oth, 4);
    }
    float a1;
    {
        bool hi = lane & 8;
        float mine = hi ? a2[1] : a2[0];
        float oth  = hi ? a2[0] : a2[1];
        a1 = mine + __shfl_xor(oth, 8);
    }
    a1 += __shfl_xor(a1, 16);
    a1 += __shfl_xor(a1, 32);
    // lane l holds full dot for p = l & 15

    // softmax over the 16-lane group
    float m = a1;
#pragma unroll
    for (int off = 1; off < 16; off <<= 1) m = fmaxf(m, __shfl_xor(m, off));
    float e = __expf((a1 - m) * 0.25f);
    float den = e;
#pragma unroll
    for (int off = 1; off < 16; off <<= 1) den += __shfl_xor(den, off);

    if (lane < P) {
        prods[(size_t)wid * P + lane] = a1;
        wgt  [(size_t)wid * P + lane] = e / den;
    }
}

// ---------------------------------------------------------------------------
// Kernel 2: chunk totals T[b,c,p,d]. Block = (b,c), thread = d.
// x rows preloaded (32 independent loads in flight); prods via uniform-address
// float4 loads (compiler scalarizes to s_load -> SGPR broadcast).
// ---------------------------------------------------------------------------
__global__ __launch_bounds__(512) void k_totals(const float* __restrict__ x,
                                                const float* __restrict__ prods,
                                                float* __restrict__ T) {
    int c = blockIdx.x & (NC - 1);
    int b = blockIdx.x >> 6;
    int d = threadIdx.x;
    int bs0 = b * S + c * CL;

    float xv[CL];
#pragma unroll
    for (int i = 0; i < CL; ++i) xv[i] = x[(size_t)(bs0 + i) * D + d];

    float acc[P];
#pragma unroll
    for (int p = 0; p < P; ++p) acc[p] = 0.f;

#pragma unroll
    for (int i = 0; i < CL; ++i) {
        const float4* pp = (const float4*)(prods + (size_t)(bs0 + i) * P);
        float pr[P];
        ((float4*)pr)[0] = pp[0];
        ((float4*)pr)[1] = pp[1];
        ((float4*)pr)[2] = pp[2];
        ((float4*)pr)[3] = pp[3];
#pragma unroll
        for (int p = 0; p < P; ++p) acc[p] = fmaf(pr[p], xv[i], acc[p]);
    }
    size_t tb = ((size_t)(b * NC + c)) * (P * D) + d;
#pragma unroll
    for (int p = 0; p < P; ++p) T[tb + p * D] = acc[p];
}

// ---------------------------------------------------------------------------
// Kernel 3: in-place exclusive prefix over chunks. Thread = (b,p,d).
// All 64 chunk values preloaded -> 64 loads in flight, then stores.
// ---------------------------------------------------------------------------
__global__ __launch_bounds__(128) void k_scan(float* __restrict__ T) {
    int t = blockIdx.x * blockDim.x + threadIdx.x;   // ((b*P+p)*D + d)
    int d = t & (D - 1);
    int p = (t >> 9) & (P - 1);
    int b = t >> 13;
    size_t base = ((size_t)b * NC * P + p) * D + d;

    float v[NC];
#pragma unroll
    for (int c = 0; c < NC; ++c) v[c] = T[base + (size_t)c * (P * D)];

    float run = 0.f;
#pragma unroll
    for (int c = 0; c < NC; ++c) {
        T[base + (size_t)c * (P * D)] = run;
        run += v[c];
    }
}

// ---------------------------------------------------------------------------
// Kernel 4: apply. Block = (b,c), thread = d. x rows preloaded; prods/w via
// uniform-address loads; fused softmax-weighted output.
// ---------------------------------------------------------------------------
__global__ __launch_bounds__(512) void k_apply(const float* __restrict__ x,
                                               const float* __restrict__ prods,
                                               const float* __restrict__ wgt,
                                               const float* __restrict__ T,
                                               float* __restrict__ out) {
    int c = blockIdx.x & (NC - 1);
    int b = blockIdx.x >> 6;
    int d = threadIdx.x;
    int bs0 = b * S + c * CL;

    float xv[CL];
#pragma unroll
    for (int i = 0; i < CL; ++i) xv[i] = x[(size_t)(bs0 + i) * D + d];

    float st[P];
    size_t tb = ((size_t)(b * NC + c)) * (P * D) + d;
#pragma unroll
    for (int p = 0; p < P; ++p) st[p] = T[tb + p * D];

#pragma unroll
    for (int i = 0; i < CL; ++i) {
        const int bs = bs0 + i;
        const float4* pp = (const float4*)(prods + (size_t)bs * P);
        const float4* wp = (const float4*)(wgt   + (size_t)bs * P);
        float pr[P], ww[P];
        ((float4*)pr)[0] = pp[0];
        ((float4*)pr)[1] = pp[1];
        ((float4*)pr)[2] = pp[2];
        ((float4*)pr)[3] = pp[3];
        ((float4*)ww)[0] = wp[0];
        ((float4*)ww)[1] = wp[1];
        ((float4*)ww)[2] = wp[2];
        ((float4*)ww)[3] = wp[3];
        float o = 0.f;
#pragma unroll
        for (int p = 0; p < P; ++p) {
            st[p] = fmaf(pr[p], xv[i], st[p]);
            o = fmaf(ww[p], st[p], o);
        }
        __builtin_nontemporal_store(o, &out[(size_t)bs * D + d]);
    }
}

extern "C" void kernel_launch(void* const* d_in, const int* in_sizes, int n_in,
                              void* d_out, int out_size, void* d_ws, size_t ws_size,
                              hipStream_t stream) {
    const float* x     = (const float*)d_in[0];
    const float* proxy = (const float*)d_in[1];
    float* out   = (float*)d_out;

    float* prods = (float*)d_ws;                 // B*S*P floats = 512 KiB
    float* wgt   = prods + (size_t)B * S * P;    // 512 KiB
    float* T     = wgt   + (size_t)B * S * P;    // B*NC*P*D floats = 8 MiB

    k_prods <<<(B * S) / 4,        256, 0, stream>>>(x, proxy, prods, wgt);
    k_totals<<<B * NC,             512, 0, stream>>>(x, prods, T);
    k_scan  <<<(B * P * D) / 128,  128, 0, stream>>>(T);
    k_apply <<<B * NC,             512, 0, stream>>>(x, prods, wgt, T, out);
}

// Round 4
// 40.238 us; speedup vs baseline: 2.7935x; 1.3493x over previous
//
#include <hip/hip_runtime.h>
#include <hip/hip_bf16.h>

#define B 4
#define S 2048
#define D 512
#define P 16
#define NC 64   // chunks over sequence
#define CL 32   // chunk length = S/NC

// ---------------------------------------------------------------------------
// Kernel 1: prods[b,s,p] = dot(proxy[p,:], x[b,s,:]); w = softmax_p(prods/4)
// One wave (64 lanes) per (b,s). Lane owns 8 contiguous d. Butterfly reduce.
// (verbatim from R1 baseline, 40.9 us)
// ---------------------------------------------------------------------------
__global__ __launch_bounds__(256) void k_prods(const float* __restrict__ x,
                                               const float* __restrict__ proxy,
                                               float* __restrict__ prods,
                                               float* __restrict__ wgt) {
    int wid  = (blockIdx.x * blockDim.x + threadIdx.x) >> 6;  // bs index 0..B*S-1
    int lane = threadIdx.x & 63;
    if (wid >= B * S) return;

    const float* xr = x + (size_t)wid * D + lane * 8;
    float4 xa = *(const float4*)xr;
    float4 xb = *(const float4*)(xr + 4);

    float part[P];
#pragma unroll
    for (int p = 0; p < P; ++p) {
        const float* pr = proxy + p * D + lane * 8;
        float4 pa = *(const float4*)pr;
        float4 pb = *(const float4*)(pr + 4);
        part[p] = xa.x*pa.x + xa.y*pa.y + xa.z*pa.z + xa.w*pa.w
                + xb.x*pb.x + xb.y*pb.y + xb.z*pb.z + xb.w*pb.w;
    }
#pragma unroll
    for (int p = 0; p < P; ++p) {
        float v = part[p];
#pragma unroll
        for (int off = 32; off > 0; off >>= 1) v += __shfl_xor(v, off);
        part[p] = v;
    }
    float m = part[0];
#pragma unroll
    for (int p = 1; p < P; ++p) m = fmaxf(m, part[p]);
    float e[P];
    float den = 0.f;
#pragma unroll
    for (int p = 0; p < P; ++p) { e[p] = __expf((part[p] - m) * 0.25f); den += e[p]; }
    float inv = 1.f / den;

    int lp = lane & 15;
    float myp = part[0], mye = e[0];
#pragma unroll
    for (int p = 1; p < P; ++p) {
        bool sel = (lp == p);
        myp = sel ? part[p] : myp;
        mye = sel ? e[p]    : mye;
    }
    if (lane < P) {
        prods[(size_t)wid * P + lane] = myp;
        wgt  [(size_t)wid * P + lane] = mye * inv;
    }
}

// ---------------------------------------------------------------------------
// Kernel 2: chunk totals T[b,c,p,d]. Block = (b,c,half), 256 threads,
// thread = d within half. 512 blocks -> 2 blocks/CU -> 4 waves/SIMD.
// ---------------------------------------------------------------------------
__global__ __launch_bounds__(256) void k_totals(const float* __restrict__ x,
                                                const float* __restrict__ prods,
                                                float* __restrict__ T) {
    int h = blockIdx.x & 1;
    int c = (blockIdx.x >> 1) & (NC - 1);
    int b = blockIdx.x >> 7;
    int d = h * 256 + threadIdx.x;

    float acc[P];
#pragma unroll
    for (int p = 0; p < P; ++p) acc[p] = 0.f;

    int bs0 = b * S + c * CL;
#pragma unroll 4
    for (int i = 0; i < CL; ++i) {
        int bs = bs0 + i;
        float xv = x[(size_t)bs * D + d];
        const float4* pp = (const float4*)(prods + (size_t)bs * P);
        float pr[P];
        ((float4*)pr)[0] = pp[0];
        ((float4*)pr)[1] = pp[1];
        ((float4*)pr)[2] = pp[2];
        ((float4*)pr)[3] = pp[3];
#pragma unroll
        for (int p = 0; p < P; ++p) acc[p] = fmaf(pr[p], xv, acc[p]);
    }
    size_t tb = ((size_t)(b * NC + c)) * (P * D) + d;
#pragma unroll
    for (int p = 0; p < P; ++p) T[tb + p * D] = acc[p];
}

// ---------------------------------------------------------------------------
// Kernel 3: in-place exclusive prefix over chunks (verbatim R1).
// ---------------------------------------------------------------------------
__global__ __launch_bounds__(256) void k_scan(float* __restrict__ T) {
    int t = blockIdx.x * blockDim.x + threadIdx.x;   // ((b*P+p)*D + d)
    int d = t & (D - 1);
    int p = (t >> 9) & (P - 1);
    int b = t >> 13;
    size_t base = ((size_t)b * NC * P + p) * D + d;
    float run = 0.f;
#pragma unroll 8
    for (int c = 0; c < NC; ++c) {
        size_t idx = base + (size_t)c * (P * D);
        float v = T[idx];
        T[idx] = run;
        run += v;
    }
}

// ---------------------------------------------------------------------------
// Kernel 4: apply. Block = (b,c,half), 256 threads, thread = d within half.
// ---------------------------------------------------------------------------
__global__ __launch_bounds__(256) void k_apply(const float* __restrict__ x,
                                               const float* __restrict__ prods,
                                               const float* __restrict__ wgt,
                                               const float* __restrict__ T,
                                               float* __restrict__ out) {
    int h = blockIdx.x & 1;
    int c = (blockIdx.x >> 1) & (NC - 1);
    int b = blockIdx.x >> 7;
    int d = h * 256 + threadIdx.x;

    float st[P];
    size_t tb = ((size_t)(b * NC + c)) * (P * D) + d;
#pragma unroll
    for (int p = 0; p < P; ++p) st[p] = T[tb + p * D];

    int bs0 = b * S + c * CL;
#pragma unroll 2
    for (int i = 0; i < CL; ++i) {
        int bs = bs0 + i;
        float xv = x[(size_t)bs * D + d];
        const float4* pp = (const float4*)(prods + (size_t)bs * P);
        const float4* wp = (const float4*)(wgt   + (size_t)bs * P);
        float pr[P], ww[P];
        ((float4*)pr)[0] = pp[0];
        ((float4*)pr)[1] = pp[1];
        ((float4*)pr)[2] = pp[2];
        ((float4*)pr)[3] = pp[3];
        ((float4*)ww)[0] = wp[0];
        ((float4*)ww)[1] = wp[1];
        ((float4*)ww)[2] = wp[2];
        ((float4*)ww)[3] = wp[3];
        float o = 0.f;
#pragma unroll
        for (int p = 0; p < P; ++p) {
            st[p] = fmaf(pr[p], xv, st[p]);
            o = fmaf(ww[p], st[p], o);
        }
        out[(size_t)bs * D + d] = o;
    }
}

extern "C" void kernel_launch(void* const* d_in, const int* in_sizes, int n_in,
                              void* d_out, int out_size, void* d_ws, size_t ws_size,
                              hipStream_t stream) {
    const float* x     = (const float*)d_in[0];
    const float* proxy = (const float*)d_in[1];
    float* out   = (float*)d_out;

    float* prods = (float*)d_ws;                 // B*S*P floats = 512 KiB
    float* wgt   = prods + (size_t)B * S * P;    // 512 KiB
    float* T     = wgt   + (size_t)B * S * P;    // B*NC*P*D floats = 8 MiB

    k_prods <<<(B * S) / 4,       256, 0, stream>>>(x, proxy, prods, wgt);
    k_totals<<<B * NC * 2,        256, 0, stream>>>(x, prods, T);
    k_scan  <<<(B * P * D) / 256, 256, 0, stream>>>(T);
    k_apply <<<B * NC * 2,        256, 0, stream>>>(x, prods, wgt, T, out);
}